// Round 1
// baseline (690.533 us; speedup 1.0000x reference)
//
#include <hip/hip_runtime.h>

// SparseMoE: T=4096 tokens, D=1024, E=8 experts, H=2048, top_k=2.
// Plan: fp64-accurate gating + routing lists -> per-expert gathered bf16 MFMA
// GEMM (128x128 tile, 4 waves, 16x16x32) -> atomicAdd scatter (2 commutative
// adds per element onto zeroed out => deterministic). Variance via atomics.

#define NTOK 4096
#define DIM  1024
#define NEXP 8
#define HID  2048

#define BM 128
#define BN 128
#define BK 32
#define LDS_STRIDE 40   // bf16 elems; 80B row stride -> 16B aligned, conflict-light

using u16   = unsigned short;
using u16x8 = __attribute__((ext_vector_type(8))) unsigned short;
using bf16x8 = __attribute__((ext_vector_type(8))) __bf16;
using f32x4  = __attribute__((ext_vector_type(4))) float;

__device__ inline u16 f2bf(float f) {
  union { float f; unsigned u; } v; v.f = f;
  unsigned r = v.u + 0x7fffu + ((v.u >> 16) & 1u);  // RNE, no NaN in this data
  return (u16)(r >> 16);
}

// ---------------- gating: fp64 logits, softmax, top-2, routing lists ---------
__global__ __launch_bounds__(256) void gate_kernel(
    const float* __restrict__ x, const float* __restrict__ gW,
    const float* __restrict__ gb, int* __restrict__ counts,
    float* __restrict__ sums, float* __restrict__ sumsq,
    int* __restrict__ lists) {
  const int wave = threadIdx.x >> 6;
  const int lane = threadIdx.x & 63;
  const int t = blockIdx.x * 4 + wave;

  const float4* xrow = (const float4*)(x + (size_t)t * DIM);
  double acc[NEXP];
#pragma unroll
  for (int e = 0; e < NEXP; ++e) acc[e] = 0.0;

#pragma unroll
  for (int c = 0; c < 4; ++c) {
    int idx = c * 64 + lane;          // float4 index; d = 4*idx
    float4 xv = xrow[idx];
#pragma unroll
    for (int e = 0; e < NEXP; ++e) {
      float4 wv = ((const float4*)(gW + (size_t)e * DIM))[idx];
      acc[e] += (double)xv.x * wv.x + (double)xv.y * wv.y +
                (double)xv.z * wv.z + (double)xv.w * wv.w;
    }
  }
#pragma unroll
  for (int e = 0; e < NEXP; ++e) {
    double v = acc[e];
#pragma unroll
    for (int off = 32; off > 0; off >>= 1) v += __shfl_down(v, off);
    acc[e] = v;  // valid on lane 0
  }

  if (lane == 0) {
    double logits[NEXP];
#pragma unroll
    for (int e = 0; e < NEXP; ++e) logits[e] = acc[e] + (double)gb[e];
    double m = logits[0];
#pragma unroll
    for (int e = 1; e < NEXP; ++e) m = fmax(m, logits[e]);
    double p[NEXP], s = 0.0;
#pragma unroll
    for (int e = 0; e < NEXP; ++e) { p[e] = exp(logits[e] - m); s += p[e]; }
#pragma unroll
    for (int e = 0; e < NEXP; ++e) p[e] /= s;

    // top-2 (ties -> lower index, matching lax.top_k)
    int i1 = 0;
#pragma unroll
    for (int e = 1; e < NEXP; ++e) if (p[e] > p[i1]) i1 = e;
    int i2 = (i1 == 0) ? 1 : 0;
#pragma unroll
    for (int e = 0; e < NEXP; ++e) {
      if (e != i1 && p[e] > p[i2]) i2 = e;
    }

#pragma unroll
    for (int e = 0; e < NEXP; ++e) {
      float pf = (float)p[e];
      atomicAdd(&sums[e], pf);
      atomicAdd(&sumsq[e], pf * pf);
    }
    int pos1 = atomicAdd(&counts[i1], 1);
    lists[i1 * NTOK + pos1] = t;
    int pos2 = atomicAdd(&counts[i2], 1);
    lists[i2 * NTOK + pos2] = t;
  }
}

// ---------------- variance finalize (ddof=1) ---------------------------------
__global__ void var_kernel(const float* __restrict__ sums,
                           const float* __restrict__ sumsq,
                           float* __restrict__ var_out) {
  int e = threadIdx.x;
  if (e < NEXP) {
    double s = (double)sums[e], q = (double)sumsq[e];
    double var = (q - s * s / (double)NTOK) / (double)(NTOK - 1);
    var_out[e] = (float)var;
  }
}

// ---------------- gathered expert GEMM: bf16 MFMA 128x128 tile ---------------
__global__ __launch_bounds__(256, 2) void expert_gemm(
    const float* __restrict__ x, const float* __restrict__ eW,
    const float* __restrict__ eb, const int* __restrict__ counts,
    const int* __restrict__ lists, float* __restrict__ out) {
  __shared__ u16 As[BM][LDS_STRIDE];
  __shared__ u16 Bs[BN][LDS_STRIDE];
  __shared__ int tok[BM];

  const int bid = blockIdx.x;
  const int e  = bid >> 9;          // 512 blocks per expert (32 rb x 16 cb)
  const int rb = (bid >> 4) & 31;
  const int cb = bid & 15;
  const int cnt = counts[e];
  if (rb * BM >= cnt) return;

  const int tid = threadIdx.x;
  if (tid < BM) {
    int gi = rb * BM + tid;
    tok[tid] = (gi < cnt) ? lists[e * NTOK + gi] : -1;
  }
  __syncthreads();

  // staging assignment: thread -> (row, 16-elem k-chunk)
  const int r  = tid >> 1;
  const int kc = (tid & 1) << 4;
  const int trow = tok[r];
  const float* arow = (trow >= 0) ? (x + (size_t)trow * DIM) : x;  // dummy if pad
  const float* brow = eW + ((size_t)e * HID + (size_t)cb * BN + r) * DIM;
  const bool valid_a = (trow >= 0);

  // wave -> 64x64 quadrant
  const int wave = tid >> 6;
  const int lane = tid & 63;
  const int wm = (wave >> 1) * 64;
  const int wn = (wave & 1) * 64;
  const int lr = lane & 15;
  const int lk = (lane >> 4) * 8;

  f32x4 acc[4][4];
#pragma unroll
  for (int m = 0; m < 4; ++m)
#pragma unroll
    for (int n = 0; n < 4; ++n) acc[m][n] = (f32x4)(0.0f);

  for (int kt = 0; kt < DIM / BK; ++kt) {
    const int k0 = kt * BK;

    float va[16], vb[16];
    {
      const float4* s = (const float4*)(arow + k0 + kc);
#pragma unroll
      for (int j = 0; j < 4; ++j) {
        float4 v = s[j];
        va[4 * j + 0] = v.x; va[4 * j + 1] = v.y;
        va[4 * j + 2] = v.z; va[4 * j + 3] = v.w;
      }
      if (!valid_a) {
#pragma unroll
        for (int j = 0; j < 16; ++j) va[j] = 0.0f;
      }
      const float4* s2 = (const float4*)(brow + k0 + kc);
#pragma unroll
      for (int j = 0; j < 4; ++j) {
        float4 v = s2[j];
        vb[4 * j + 0] = v.x; vb[4 * j + 1] = v.y;
        vb[4 * j + 2] = v.z; vb[4 * j + 3] = v.w;
      }
    }
    u16x8 pa0, pa1, pb0, pb1;
#pragma unroll
    for (int j = 0; j < 8; ++j) {
      pa0[j] = f2bf(va[j]);     pa1[j] = f2bf(va[8 + j]);
      pb0[j] = f2bf(vb[j]);     pb1[j] = f2bf(vb[8 + j]);
    }
    *(u16x8*)&As[r][kc]     = pa0;
    *(u16x8*)&As[r][kc + 8] = pa1;
    *(u16x8*)&Bs[r][kc]     = pb0;
    *(u16x8*)&Bs[r][kc + 8] = pb1;

    __syncthreads();

    bf16x8 fa[4], fb[4];
#pragma unroll
    for (int m = 0; m < 4; ++m)
      fa[m] = *(const bf16x8*)&As[wm + m * 16 + lr][lk];
#pragma unroll
    for (int n = 0; n < 4; ++n)
      fb[n] = *(const bf16x8*)&Bs[wn + n * 16 + lr][lk];

#pragma unroll
    for (int m = 0; m < 4; ++m)
#pragma unroll
      for (int n = 0; n < 4; ++n)
        acc[m][n] = __builtin_amdgcn_mfma_f32_16x16x32_bf16(
            fa[m], fb[n], acc[m][n], 0, 0, 0);

    __syncthreads();
  }

  // epilogue: out[token, h] += 0.5*(dot + bias)  (2 commutative adds/elem)
#pragma unroll
  for (int n = 0; n < 4; ++n) {
    const int hcol = cb * BN + wn + n * 16 + lr;
    const float bias = eb[e * HID + hcol];
#pragma unroll
    for (int m = 0; m < 4; ++m) {
#pragma unroll
      for (int i = 0; i < 4; ++i) {
        int rloc = wm + m * 16 + (lane >> 4) * 4 + i;   // C/D: row=(l>>4)*4+i
        int tr = tok[rloc];
        if (tr >= 0)
          atomicAdd(&out[(size_t)tr * HID + hcol], 0.5f * (acc[m][n][i] + bias));
      }
    }
  }
}

extern "C" void kernel_launch(void* const* d_in, const int* in_sizes, int n_in,
                              void* d_out, int out_size, void* d_ws, size_t ws_size,
                              hipStream_t stream) {
  const float* x  = (const float*)d_in[0];   // [4096,1024]
  const float* gW = (const float*)d_in[1];   // [8,1024]
  const float* gb = (const float*)d_in[2];   // [8]
  const float* eW = (const float*)d_in[3];   // [8,2048,1024]
  const float* eb = (const float*)d_in[4];   // [8,2048]
  // d_in[5] = moe_top_k (=2, hardcoded)

  float* out = (float*)d_out;
  float* var_out = out + (size_t)NTOK * HID;

  int*   counts = (int*)d_ws;
  float* sums   = (float*)((char*)d_ws + 32);
  float* sumsq  = (float*)((char*)d_ws + 64);
  int*   lists  = (int*)((char*)d_ws + 128);  // 8 * 4096 ints

  hipMemsetAsync(d_out, 0, (size_t)out_size * sizeof(float), stream);
  hipMemsetAsync(d_ws, 0, 128, stream);

  gate_kernel<<<NTOK / 4, 256, 0, stream>>>(x, gW, gb, counts, sums, sumsq, lists);
  var_kernel<<<1, 64, 0, stream>>>(sums, sumsq, var_out);
  expert_gemm<<<NEXP * (NTOK / BM) * (HID / BN), 256, 0, stream>>>(
      x, eW, eb, counts, lists, out);
}

// Round 2
// 179.842 us; speedup vs baseline: 3.8397x; 3.8397x over previous
//
#include <hip/hip_runtime.h>

// SparseMoE: T=4096 tokens, D=1024, E=8 experts, H=2048, top_k=2.
// R1 fix: gate atomics (550us of same-address serialization) removed.
// gate -> probs+top2 in ws; route kernel does deterministic prefix-sum
// compaction + fp64 variance; gathered bf16 MFMA expert GEMM unchanged.

#define NTOK 4096
#define DIM  1024
#define NEXP 8
#define HID  2048

#define BM 128
#define BN 128
#define BK 32
#define LDS_STRIDE 40   // bf16 elems; 80B row stride -> 16B aligned, conflict-light

using u16   = unsigned short;
using u16x8 = __attribute__((ext_vector_type(8))) unsigned short;
using bf16x8 = __attribute__((ext_vector_type(8))) __bf16;
using f32x4  = __attribute__((ext_vector_type(4))) float;

__device__ inline u16 f2bf(float f) {
  union { float f; unsigned u; } v; v.f = f;
  unsigned r = v.u + 0x7fffu + ((v.u >> 16) & 1u);  // RNE, no NaN in this data
  return (u16)(r >> 16);
}

// ---------------- gating: fp64 logits, softmax, top-2 -> ws (no atomics) -----
__global__ __launch_bounds__(256) void gate_kernel(
    const float* __restrict__ x, const float* __restrict__ gW,
    const float* __restrict__ gb, float* __restrict__ probs,
    int* __restrict__ top2) {
  const int wave = threadIdx.x >> 6;
  const int lane = threadIdx.x & 63;
  const int t = blockIdx.x * 4 + wave;

  const float4* xrow = (const float4*)(x + (size_t)t * DIM);
  double acc[NEXP];
#pragma unroll
  for (int e = 0; e < NEXP; ++e) acc[e] = 0.0;

#pragma unroll
  for (int c = 0; c < 4; ++c) {
    int idx = c * 64 + lane;          // float4 index; d = 4*idx
    float4 xv = xrow[idx];
#pragma unroll
    for (int e = 0; e < NEXP; ++e) {
      float4 wv = ((const float4*)(gW + (size_t)e * DIM))[idx];
      acc[e] += (double)xv.x * wv.x + (double)xv.y * wv.y +
                (double)xv.z * wv.z + (double)xv.w * wv.w;
    }
  }
#pragma unroll
  for (int e = 0; e < NEXP; ++e) {
    double v = acc[e];
#pragma unroll
    for (int off = 32; off > 0; off >>= 1) v += __shfl_down(v, off);
    acc[e] = v;  // valid on lane 0
  }

  if (lane == 0) {
    double logits[NEXP];
#pragma unroll
    for (int e = 0; e < NEXP; ++e) logits[e] = acc[e] + (double)gb[e];
    double m = logits[0];
#pragma unroll
    for (int e = 1; e < NEXP; ++e) m = fmax(m, logits[e]);
    double p[NEXP], s = 0.0;
#pragma unroll
    for (int e = 0; e < NEXP; ++e) { p[e] = exp(logits[e] - m); s += p[e]; }
#pragma unroll
    for (int e = 0; e < NEXP; ++e) p[e] /= s;

    // top-2 (ties -> lower index, matching lax.top_k)
    int i1 = 0;
#pragma unroll
    for (int e = 1; e < NEXP; ++e) if (p[e] > p[i1]) i1 = e;
    int i2 = (i1 == 0) ? 1 : 0;
#pragma unroll
    for (int e = 0; e < NEXP; ++e) {
      if (e != i1 && p[e] > p[i2]) i2 = e;
    }

#pragma unroll
    for (int e = 0; e < NEXP; ++e) probs[(size_t)t * NEXP + e] = (float)p[e];
    top2[t] = i1 | (i2 << 4);
  }
}

// ------- route: per-expert stable compaction (ballot prefix) + fp64 variance -
__global__ __launch_bounds__(256) void route_kernel(
    const float* __restrict__ probs, const int* __restrict__ top2,
    int* __restrict__ counts, int* __restrict__ lists,
    float* __restrict__ var_out) {
  const int e = blockIdx.x;
  const int tid = threadIdx.x;
  const int lane = tid & 63;
  const int wave = tid >> 6;

  __shared__ int wsum[4];
  __shared__ double ds[4], dq[4];

  double s = 0.0, q = 0.0;
  int base = 0;

  for (int c = 0; c < NTOK / 256; ++c) {
    int t = c * 256 + tid;
    float p = probs[(size_t)t * NEXP + e];
    s += (double)p;
    q += (double)p * (double)p;

    int m = top2[t];
    bool f = ((m & 15) == e) || (((m >> 4) & 15) == e);
    unsigned long long bal = __ballot(f);
    int before = __popcll(bal & ((1ull << lane) - 1ull));
    if (lane == 0) wsum[wave] = __popcll(bal);
    __syncthreads();
    int woff = 0;
#pragma unroll
    for (int w = 0; w < 4; ++w) if (w < wave) woff += wsum[w];
    int ctotal = wsum[0] + wsum[1] + wsum[2] + wsum[3];
    if (f) lists[e * NTOK + base + woff + before] = t;
    base += ctotal;
    __syncthreads();
  }
  if (tid == 0) counts[e] = base;

  // variance (ddof=1) in fp64
#pragma unroll
  for (int off = 32; off > 0; off >>= 1) {
    s += __shfl_down(s, off);
    q += __shfl_down(q, off);
  }
  if (lane == 0) { ds[wave] = s; dq[wave] = q; }
  __syncthreads();
  if (tid == 0) {
    double S = ds[0] + ds[1] + ds[2] + ds[3];
    double Q = dq[0] + dq[1] + dq[2] + dq[3];
    var_out[e] = (float)((Q - S * S / (double)NTOK) / (double)(NTOK - 1));
  }
}

// ---------------- gathered expert GEMM: bf16 MFMA 128x128 tile ---------------
__global__ __launch_bounds__(256, 2) void expert_gemm(
    const float* __restrict__ x, const float* __restrict__ eW,
    const float* __restrict__ eb, const int* __restrict__ counts,
    const int* __restrict__ lists, float* __restrict__ out) {
  __shared__ u16 As[BM][LDS_STRIDE];
  __shared__ u16 Bs[BN][LDS_STRIDE];
  __shared__ int tok[BM];

  const int bid = blockIdx.x;
  const int e  = bid >> 9;          // 512 blocks per expert (32 rb x 16 cb)
  const int rb = (bid >> 4) & 31;
  const int cb = bid & 15;
  const int cnt = counts[e];
  if (rb * BM >= cnt) return;

  const int tid = threadIdx.x;
  if (tid < BM) {
    int gi = rb * BM + tid;
    tok[tid] = (gi < cnt) ? lists[e * NTOK + gi] : -1;
  }
  __syncthreads();

  // staging assignment: thread -> (row, 16-elem k-chunk)
  const int r  = tid >> 1;
  const int kc = (tid & 1) << 4;
  const int trow = tok[r];
  const float* arow = (trow >= 0) ? (x + (size_t)trow * DIM) : x;  // dummy if pad
  const float* brow = eW + ((size_t)e * HID + (size_t)cb * BN + r) * DIM;
  const bool valid_a = (trow >= 0);

  // wave -> 64x64 quadrant
  const int wave = tid >> 6;
  const int lane = tid & 63;
  const int wm = (wave >> 1) * 64;
  const int wn = (wave & 1) * 64;
  const int lr = lane & 15;
  const int lk = (lane >> 4) * 8;

  f32x4 acc[4][4];
#pragma unroll
  for (int m = 0; m < 4; ++m)
#pragma unroll
    for (int n = 0; n < 4; ++n) acc[m][n] = (f32x4)(0.0f);

  for (int kt = 0; kt < DIM / BK; ++kt) {
    const int k0 = kt * BK;

    float va[16], vb[16];
    {
      const float4* s = (const float4*)(arow + k0 + kc);
#pragma unroll
      for (int j = 0; j < 4; ++j) {
        float4 v = s[j];
        va[4 * j + 0] = v.x; va[4 * j + 1] = v.y;
        va[4 * j + 2] = v.z; va[4 * j + 3] = v.w;
      }
      if (!valid_a) {
#pragma unroll
        for (int j = 0; j < 16; ++j) va[j] = 0.0f;
      }
      const float4* s2 = (const float4*)(brow + k0 + kc);
#pragma unroll
      for (int j = 0; j < 4; ++j) {
        float4 v = s2[j];
        vb[4 * j + 0] = v.x; vb[4 * j + 1] = v.y;
        vb[4 * j + 2] = v.z; vb[4 * j + 3] = v.w;
      }
    }
    u16x8 pa0, pa1, pb0, pb1;
#pragma unroll
    for (int j = 0; j < 8; ++j) {
      pa0[j] = f2bf(va[j]);     pa1[j] = f2bf(va[8 + j]);
      pb0[j] = f2bf(vb[j]);     pb1[j] = f2bf(vb[8 + j]);
    }
    *(u16x8*)&As[r][kc]     = pa0;
    *(u16x8*)&As[r][kc + 8] = pa1;
    *(u16x8*)&Bs[r][kc]     = pb0;
    *(u16x8*)&Bs[r][kc + 8] = pb1;

    __syncthreads();

    bf16x8 fa[4], fb[4];
#pragma unroll
    for (int m = 0; m < 4; ++m)
      fa[m] = *(const bf16x8*)&As[wm + m * 16 + lr][lk];
#pragma unroll
    for (int n = 0; n < 4; ++n)
      fb[n] = *(const bf16x8*)&Bs[wn + n * 16 + lr][lk];

#pragma unroll
    for (int m = 0; m < 4; ++m)
#pragma unroll
      for (int n = 0; n < 4; ++n)
        acc[m][n] = __builtin_amdgcn_mfma_f32_16x16x32_bf16(
            fa[m], fb[n], acc[m][n], 0, 0, 0);

    __syncthreads();
  }

  // epilogue: out[token, h] += 0.5*(dot + bias)  (2 commutative adds/elem)
#pragma unroll
  for (int n = 0; n < 4; ++n) {
    const int hcol = cb * BN + wn + n * 16 + lr;
    const float bias = eb[e * HID + hcol];
#pragma unroll
    for (int m = 0; m < 4; ++m) {
#pragma unroll
      for (int i = 0; i < 4; ++i) {
        int rloc = wm + m * 16 + (lane >> 4) * 4 + i;   // C/D: row=(l>>4)*4+i
        int tr = tok[rloc];
        if (tr >= 0)
          atomicAdd(&out[(size_t)tr * HID + hcol], 0.5f * (acc[m][n][i] + bias));
      }
    }
  }
}

extern "C" void kernel_launch(void* const* d_in, const int* in_sizes, int n_in,
                              void* d_out, int out_size, void* d_ws, size_t ws_size,
                              hipStream_t stream) {
  const float* x  = (const float*)d_in[0];   // [4096,1024]
  const float* gW = (const float*)d_in[1];   // [8,1024]
  const float* gb = (const float*)d_in[2];   // [8]
  const float* eW = (const float*)d_in[3];   // [8,2048,1024]
  const float* eb = (const float*)d_in[4];   // [8,2048]
  // d_in[5] = moe_top_k (=2, hardcoded)

  float* out = (float*)d_out;
  float* var_out = out + (size_t)NTOK * HID;

  // ws layout: counts[8] | lists[8*4096] | probs[4096*8] | top2[4096]
  int*   counts = (int*)d_ws;
  int*   lists  = (int*)((char*)d_ws + 128);
  float* probs  = (float*)((char*)d_ws + 128 + NEXP * NTOK * sizeof(int));
  int*   top2   = (int*)((char*)probs + (size_t)NTOK * NEXP * sizeof(float));

  hipMemsetAsync(d_out, 0, (size_t)out_size * sizeof(float), stream);

  gate_kernel<<<NTOK / 4, 256, 0, stream>>>(x, gW, gb, probs, top2);
  route_kernel<<<NEXP, 256, 0, stream>>>(probs, top2, counts, lists, var_out);
  expert_gemm<<<NEXP * (NTOK / BM) * (HID / BN), 256, 0, stream>>>(
      x, eW, eb, counts, lists, out);
}

// Round 3
// 150.672 us; speedup vs baseline: 4.5830x; 1.1936x over previous
//
#include <hip/hip_runtime.h>

// SparseMoE: T=4096, D=1024, E=8, H=2048, top_k=2.
// R3: pre-convert x/eW to bf16 in ws; expert GEMM restructured to the
// m97 pattern: global_load_lds dwordx4 staging (linear LDS dest,
// inverse-XOR-swizzled global source), swizzled conflict-free ds_read_b128,
// BK=64, 4-wave 128x128 tile, atomicAdd scatter epilogue.

#define NTOK 4096
#define DIM  1024
#define NEXP 8
#define HID  2048

#define BM 128
#define BN 128
#define BK 64

using u16    = unsigned short;
using u16x8  = __attribute__((ext_vector_type(8))) unsigned short;
using bf16x8 = __attribute__((ext_vector_type(8))) __bf16;
using f32x4  = __attribute__((ext_vector_type(4))) float;

typedef const __attribute__((address_space(1))) unsigned char* gas1p;
typedef __attribute__((address_space(3))) unsigned char* gas3p;

__device__ __forceinline__ void gload16(void* lds, const void* g) {
  __builtin_amdgcn_global_load_lds((gas1p)g, (gas3p)lds, 16, 0, 0);
}

__device__ inline u16 f2bf(float f) {
  union { float f; unsigned u; } v; v.f = f;
  unsigned r = v.u + 0x7fffu + ((v.u >> 16) & 1u);  // RNE, no NaN in this data
  return (u16)(r >> 16);
}

// ---------------- fp32 -> bf16 bulk convert (8 elems/thread) -----------------
__global__ __launch_bounds__(256) void convert_bf16(
    const float* __restrict__ in, u16* __restrict__ out) {
  int i = blockIdx.x * 256 + threadIdx.x;
  const float4* p = (const float4*)in + (size_t)i * 2;
  float4 a = p[0], b = p[1];
  u16x8 r;
  r[0] = f2bf(a.x); r[1] = f2bf(a.y); r[2] = f2bf(a.z); r[3] = f2bf(a.w);
  r[4] = f2bf(b.x); r[5] = f2bf(b.y); r[6] = f2bf(b.z); r[7] = f2bf(b.w);
  *((u16x8*)out + i) = r;
}

// ---------------- gating: fp64 logits, softmax, top-2 -> ws (no atomics) -----
__global__ __launch_bounds__(256) void gate_kernel(
    const float* __restrict__ x, const float* __restrict__ gW,
    const float* __restrict__ gb, float* __restrict__ probs,
    int* __restrict__ top2) {
  const int wave = threadIdx.x >> 6;
  const int lane = threadIdx.x & 63;
  const int t = blockIdx.x * 4 + wave;

  const float4* xrow = (const float4*)(x + (size_t)t * DIM);
  double acc[NEXP];
#pragma unroll
  for (int e = 0; e < NEXP; ++e) acc[e] = 0.0;

#pragma unroll
  for (int c = 0; c < 4; ++c) {
    int idx = c * 64 + lane;
    float4 xv = xrow[idx];
#pragma unroll
    for (int e = 0; e < NEXP; ++e) {
      float4 wv = ((const float4*)(gW + (size_t)e * DIM))[idx];
      acc[e] += (double)xv.x * wv.x + (double)xv.y * wv.y +
                (double)xv.z * wv.z + (double)xv.w * wv.w;
    }
  }
#pragma unroll
  for (int e = 0; e < NEXP; ++e) {
    double v = acc[e];
#pragma unroll
    for (int off = 32; off > 0; off >>= 1) v += __shfl_down(v, off);
    acc[e] = v;
  }

  if (lane == 0) {
    double logits[NEXP];
#pragma unroll
    for (int e = 0; e < NEXP; ++e) logits[e] = acc[e] + (double)gb[e];
    double m = logits[0];
#pragma unroll
    for (int e = 1; e < NEXP; ++e) m = fmax(m, logits[e]);
    double p[NEXP], s = 0.0;
#pragma unroll
    for (int e = 0; e < NEXP; ++e) { p[e] = exp(logits[e] - m); s += p[e]; }
#pragma unroll
    for (int e = 0; e < NEXP; ++e) p[e] /= s;

    int i1 = 0;
#pragma unroll
    for (int e = 1; e < NEXP; ++e) if (p[e] > p[i1]) i1 = e;
    int i2 = (i1 == 0) ? 1 : 0;
#pragma unroll
    for (int e = 0; e < NEXP; ++e) {
      if (e != i1 && p[e] > p[i2]) i2 = e;
    }

#pragma unroll
    for (int e = 0; e < NEXP; ++e) probs[(size_t)t * NEXP + e] = (float)p[e];
    top2[t] = i1 | (i2 << 4);
  }
}

// ------- route: per-expert stable compaction (ballot prefix) + fp64 variance -
__global__ __launch_bounds__(256) void route_kernel(
    const float* __restrict__ probs, const int* __restrict__ top2,
    int* __restrict__ counts, int* __restrict__ lists,
    float* __restrict__ var_out) {
  const int e = blockIdx.x;
  const int tid = threadIdx.x;
  const int lane = tid & 63;
  const int wave = tid >> 6;

  __shared__ int wsum[4];
  __shared__ double ds[4], dq[4];

  double s = 0.0, q = 0.0;
  int base = 0;

  for (int c = 0; c < NTOK / 256; ++c) {
    int t = c * 256 + tid;
    float p = probs[(size_t)t * NEXP + e];
    s += (double)p;
    q += (double)p * (double)p;

    int m = top2[t];
    bool f = ((m & 15) == e) || (((m >> 4) & 15) == e);
    unsigned long long bal = __ballot(f);
    int before = __popcll(bal & ((1ull << lane) - 1ull));
    if (lane == 0) wsum[wave] = __popcll(bal);
    __syncthreads();
    int woff = 0;
#pragma unroll
    for (int w = 0; w < 4; ++w) if (w < wave) woff += wsum[w];
    int ctotal = wsum[0] + wsum[1] + wsum[2] + wsum[3];
    if (f) lists[e * NTOK + base + woff + before] = t;
    base += ctotal;
    __syncthreads();
  }
  if (tid == 0) counts[e] = base;

#pragma unroll
  for (int off = 32; off > 0; off >>= 1) {
    s += __shfl_down(s, off);
    q += __shfl_down(q, off);
  }
  if (lane == 0) { ds[wave] = s; dq[wave] = q; }
  __syncthreads();
  if (tid == 0) {
    double S = ds[0] + ds[1] + ds[2] + ds[3];
    double Q = dq[0] + dq[1] + dq[2] + dq[3];
    var_out[e] = (float)((Q - S * S / (double)NTOK) / (double)(NTOK - 1));
  }
}

// --------- gathered expert GEMM: bf16, global_load_lds, swizzled LDS ---------
// LDS tile layout (A and B identical): logical [128 rows][64 cols] bf16,
// stored row-major 128B/row with 16B-chunk swizzle: stored_c16 = c16 ^ (row&7).
// global_load_lds writes LDS linearly; the source address carries the inverse
// permutation (same XOR, it's an involution).
__global__ __launch_bounds__(256, 2) void expert_gemm(
    const u16* __restrict__ xbf, const u16* __restrict__ wbf,
    const float* __restrict__ eb, const int* __restrict__ counts,
    const int* __restrict__ lists, float* __restrict__ out) {
  __shared__ u16 As[BM * BK];   // 16 KB
  __shared__ u16 Bs[BN * BK];   // 16 KB
  __shared__ int tok[BM];

  const int bid = blockIdx.x;
  const int e  = bid >> 9;          // 512 blocks/expert: 32 rb x 16 cb
  const int rb = (bid >> 4) & 31;
  const int cb = bid & 15;
  const int cnt = counts[e];
  if (rb * BM >= cnt) return;

  const int tid  = threadIdx.x;
  const int wave = tid >> 6;
  const int lane = tid & 63;

  if (tid < BM) {
    int gi = rb * BM + tid;
    tok[tid] = (gi < cnt) ? lists[e * NTOK + gi] : -1;
  }
  __syncthreads();

  // ---- staging precompute: 4 A-issues + 4 B-issues of 16B per thread ----
  const u16* asrc[4];
  const u16* bsrc[4];
  u16* alds[4];
  u16* blds[4];
#pragma unroll
  for (int j = 0; j < 4; ++j) {
    const int idx  = (j * 4 + wave) * 64 + lane;  // 16B-chunk index in [0,1024)
    const int row  = idx >> 3;
    const int c16  = (idx & 7) ^ (row & 7);       // inverse swizzle on source
    int tr = tok[row]; if (tr < 0) tr = 0;        // clamped; row discarded later
    asrc[j] = xbf + (size_t)tr * DIM + c16 * 8;
    bsrc[j] = wbf + ((size_t)e * HID + (size_t)cb * BN + row) * DIM + c16 * 8;
    // wave-uniform LDS base for this issue (lane offset added by HW)
    alds[j] = As + (j * 4 + wave) * 512;          // 512 u16 = 1024 B
    blds[j] = Bs + (j * 4 + wave) * 512;
  }

  // ---- fragment read addresses (swizzled) ----
  const int wm = (wave >> 1) * 64;
  const int wn = (wave & 1) * 64;
  const int lr = lane & 15;
  const int hk = lane >> 4;        // k-group 0..3

  f32x4 acc[4][4];
#pragma unroll
  for (int m = 0; m < 4; ++m)
#pragma unroll
    for (int n = 0; n < 4; ++n) acc[m][n] = (f32x4)(0.0f);

  for (int k0 = 0; k0 < DIM; k0 += BK) {
#pragma unroll
    for (int j = 0; j < 4; ++j) gload16(alds[j], asrc[j] + k0);
#pragma unroll
    for (int j = 0; j < 4; ++j) gload16(blds[j], bsrc[j] + k0);

    __syncthreads();   // compiler drains vmcnt before barrier

    bf16x8 fa[2][4], fb[2][4];
#pragma unroll
    for (int kk = 0; kk < 2; ++kk) {
#pragma unroll
      for (int m = 0; m < 4; ++m) {
        const int row = wm + m * 16 + lr;
        const int c16 = (kk * 4 + hk) ^ (row & 7);
        fa[kk][m] = *(const bf16x8*)&As[row * 64 + c16 * 8];
      }
#pragma unroll
      for (int n = 0; n < 4; ++n) {
        const int row = wn + n * 16 + lr;
        const int c16 = (kk * 4 + hk) ^ (row & 7);
        fb[kk][n] = *(const bf16x8*)&Bs[row * 64 + c16 * 8];
      }
    }

#pragma unroll
    for (int kk = 0; kk < 2; ++kk)
#pragma unroll
      for (int m = 0; m < 4; ++m)
#pragma unroll
        for (int n = 0; n < 4; ++n)
          acc[m][n] = __builtin_amdgcn_mfma_f32_16x16x32_bf16(
              fa[kk][m], fb[kk][n], acc[m][n], 0, 0, 0);

    __syncthreads();
  }

  // epilogue: out[token, h] += 0.5*(dot + bias)  (2 commutative adds/elem)
#pragma unroll
  for (int n = 0; n < 4; ++n) {
    const int hcol = cb * BN + wn + n * 16 + lr;
    const float bias = eb[e * HID + hcol];
#pragma unroll
    for (int m = 0; m < 4; ++m) {
#pragma unroll
      for (int i = 0; i < 4; ++i) {
        int rloc = wm + m * 16 + hk * 4 + i;   // C/D: row=(lane>>4)*4+i
        int tr = tok[rloc];
        if (tr >= 0)
          atomicAdd(&out[(size_t)tr * HID + hcol], 0.5f * (acc[m][n][i] + bias));
      }
    }
  }
}

extern "C" void kernel_launch(void* const* d_in, const int* in_sizes, int n_in,
                              void* d_out, int out_size, void* d_ws, size_t ws_size,
                              hipStream_t stream) {
  const float* x  = (const float*)d_in[0];   // [4096,1024]
  const float* gW = (const float*)d_in[1];   // [8,1024]
  const float* gb = (const float*)d_in[2];   // [8]
  const float* eW = (const float*)d_in[3];   // [8,2048,1024]
  const float* eb = (const float*)d_in[4];   // [8,2048]

  float* out = (float*)d_out;
  float* var_out = out + (size_t)NTOK * HID;

  // ws layout
  char* ws = (char*)d_ws;
  int*   counts = (int*)ws;                                   // 32 B
  int*   lists  = (int*)(ws + 1024);                          // 128 KB
  float* probs  = (float*)(ws + 1024 + 131072);               // 128 KB
  int*   top2   = (int*)(ws + 1024 + 2 * 131072);             // 16 KB
  u16*   xbf    = (u16*)(ws + 1024 + 2 * 131072 + 16384);     // 8 MB
  u16*   wbf    = (u16*)((char*)xbf + (size_t)NTOK * DIM * 2);// 32 MB

  hipMemsetAsync(d_out, 0, (size_t)out_size * sizeof(float), stream);

  convert_bf16<<<(NEXP * HID * DIM) / (256 * 8), 256, 0, stream>>>(eW, wbf);
  convert_bf16<<<(NTOK * DIM) / (256 * 8), 256, 0, stream>>>(x, xbf);
  gate_kernel<<<NTOK / 4, 256, 0, stream>>>(x, gW, gb, probs, top2);
  route_kernel<<<NEXP, 256, 0, stream>>>(probs, top2, counts, lists, var_out);
  expert_gemm<<<NEXP * (NTOK / BM) * (HID / BN), 256, 0, stream>>>(
      xbf, wbf, eb, counts, lists, out);
}